// Round 20
// baseline (45.324 us; speedup 1.0000x reference)
//
#include <hip/hip_runtime.h>
#include <math.h>

// FlowLevel: DIM=2, half=1 -> per-layer coupling depends on scalar v = z_b.
// t(v) and u(v) (pre-sigmoid) are piecewise-LINEAR in v (ReLU MLP).
// Tabulate (t, dt/dv, u, du/dv) per node; apply uses the NEAREST node's
// tangent line (exact unless a kink falls in the half-cell).
//
// v17: apply bandwidth+conflict diet. (1) tabN 1024 (kink-half-cell error
// ~2e-3/layer, << 0.125 bf16 floor; absmax was byte-identical through 4
// prior halvings); (2) 4 chains/thread, 4096 samples/block -> 256 blocks,
// staging traffic 160->40 MB; (3) entry split into (t,u)/(dt,du) float2
// arrays: random b64 reads are ~4-way banked vs b128's ~8-way.

constexpr int kDepth = 10;
constexpr int kWidth = 128;
constexpr float kVMin = -24.0f;
constexpr float kVMax =  24.0f;

// ---------------- prep: per-layer kink sort + prefix sweep ----------------
__global__ void prep_kernel(
    const float* __restrict__ an_scale, const float* __restrict__ an_bias,
    const float* __restrict__ conv_w,
    const float* __restrict__ fc1_w, const float* __restrict__ fc1_b,
    const float* __restrict__ an1_scale, const float* __restrict__ an1_bias,
    const float* __restrict__ fc2_w, const float* __restrict__ fc2_b,
    const float* __restrict__ an2_scale, const float* __restrict__ an2_bias,
    const float* __restrict__ fc3_b, const float* __restrict__ lsf,
    float* __restrict__ meta, float* __restrict__ kv,
    float* __restrict__ CG, float* __restrict__ CB)
{
  __shared__ float sWT[128 * 129];           // transposed weights, padded
  __shared__ float sVs[128], sG[128], sB[128];
  __shared__ float sGs[128], sBs[128];       // sig*g, sig*b (sweep deltas)
  __shared__ int   sOrd[128];

  const int l = blockIdx.x;                  // layer
  const int t = threadIdx.x;                 // 0..255

  // transpose fc2_w into sWT[j][k] -- all 256 threads, coalesced
  const float* wl = fc2_w + (size_t)l * kWidth * kWidth;
#pragma unroll 8
  for (int fi = t; fi < 128 * 128; fi += 256) {
    const int k = fi >> 7, j = fi & 127;
    sWT[j * 129 + k] = wl[fi];
  }

  // per-j gate params and kink position
  if (t < 128) {
    const float s1 = an1_scale[l*kWidth + t];
    const float g = fc1_w[l*kWidth + t] / s1;
    const float b = (fc1_b[l*kWidth + t] - an1_bias[l*kWidth + t]) / s1;
    float vs, sg;
    if (g > 0.0f)      { vs = -b / g; sg =  1.0f; }
    else if (g < 0.0f) { vs = -b / g; sg = -1.0f; }
    else               { vs = (b > 0.0f) ? -1e30f : 1e30f; sg = (b > 0.0f) ? 1.0f : 0.0f; }
    sG[t] = g; sB[t] = b; sVs[t] = vs;
    sGs[t] = sg * g; sBs[t] = sg * b;
  }
  __syncthreads();

  // stable rank sort by kink position -- unrolled float4 reads (pipelined)
  if (t < 128) {
    const float my = sVs[t];
    int r = 0;
    const float4* vs4 = (const float4*)sVs;
#pragma unroll
    for (int i4 = 0; i4 < 32; ++i4) {
      float4 o = vs4[i4];
      const int ib = i4 * 4;
      r += (o.x < my) || (o.x == my && ib + 0 < t);
      r += (o.y < my) || (o.y == my && ib + 1 < t);
      r += (o.z < my) || (o.z == my && ib + 2 < t);
      r += (o.w < my) || (o.w == my && ib + 3 < t);
    }
    sOrd[r] = t;
  }
  __syncthreads();

  if (t < 128) {
    kv[l*128 + t] = sVs[sOrd[t]];

    // base C[0] (thread t owns k=t): all neg-g active, plus folded bz.
    float cg = 0.0f;
    float cb = fc2_b[l*kWidth + t] - an2_bias[l*kWidth + t];
    const float4* g4 = (const float4*)sG;
    const float4* b4 = (const float4*)sB;
#pragma unroll
    for (int j4 = 0; j4 < 32; ++j4) {
      float4 G = g4[j4], B = b4[j4];
      const int j = j4 * 4;
      float w0 = sWT[(j + 0) * 129 + t];
      float w1 = sWT[(j + 1) * 129 + t];
      float w2 = sWT[(j + 2) * 129 + t];
      float w3 = sWT[(j + 3) * 129 + t];
      if (G.x < 0.0f) { cg = fmaf(G.x, w0, cg); cb = fmaf(B.x, w0, cb); }
      if (G.y < 0.0f) { cg = fmaf(G.y, w1, cg); cb = fmaf(B.y, w1, cb); }
      if (G.z < 0.0f) { cg = fmaf(G.z, w2, cg); cb = fmaf(B.z, w2, cb); }
      if (G.w < 0.0f) { cg = fmaf(G.w, w3, cg); cb = fmaf(B.w, w3, cb); }
    }

    // sweep, software-pipelined in chunks of 4 (prefetch next chunk)
    const size_t base = (size_t)l * 129 * 128;
    int4 J = ((const int4*)sOrd)[0];
    float w0 = sWT[J.x * 129 + t];
    float w1 = sWT[J.y * 129 + t];
    float w2 = sWT[J.z * 129 + t];
    float w3 = sWT[J.w * 129 + t];
#pragma unroll 1
    for (int c = 0; c < 32; ++c) {
      const int4 Jc = J;
      const float v0 = w0, v1 = w1, v2 = w2, v3 = w3;
      if (c + 1 < 32) {
        J = ((const int4*)sOrd)[c + 1];
        w0 = sWT[J.x * 129 + t];
        w1 = sWT[J.y * 129 + t];
        w2 = sWT[J.z * 129 + t];
        w3 = sWT[J.w * 129 + t];
      }
      const int p = c * 4;
      CG[base + (size_t)(p + 0) * 128 + t] = cg;
      CB[base + (size_t)(p + 0) * 128 + t] = cb;
      cg = fmaf(sGs[Jc.x], v0, cg); cb = fmaf(sBs[Jc.x], v0, cb);
      CG[base + (size_t)(p + 1) * 128 + t] = cg;
      CB[base + (size_t)(p + 1) * 128 + t] = cb;
      cg = fmaf(sGs[Jc.y], v1, cg); cb = fmaf(sBs[Jc.y], v1, cb);
      CG[base + (size_t)(p + 2) * 128 + t] = cg;
      CB[base + (size_t)(p + 2) * 128 + t] = cb;
      cg = fmaf(sGs[Jc.z], v2, cg); cb = fmaf(sBs[Jc.z], v2, cb);
      CG[base + (size_t)(p + 3) * 128 + t] = cg;
      CB[base + (size_t)(p + 3) * 128 + t] = cb;
      cg = fmaf(sGs[Jc.w], v3, cg); cb = fmaf(sBs[Jc.w], v3, cb);
    }
    CG[base + (size_t)128 * 128 + t] = cg;
    CB[base + (size_t)128 * 128 + t] = cb;
  }

  // per-layer epilogue + affine constants
  if (t == 0) {
    meta[16 + l*4 + 0] = expf(lsf[l*2 + 0]);
    meta[16 + l*4 + 1] = expf(lsf[l*2 + 1]);
    meta[16 + l*4 + 2] = fc3_b[l*2 + 0];
    meta[16 + l*4 + 3] = fc3_b[l*2 + 1];

    const float sx = an_scale[l*2+0], sy = an_scale[l*2+1];
    const float bx = an_bias[l*2+0],  by = an_bias[l*2+1];
    const float* cw = conv_w + l*4;
    const float m00 = cw[0]/sx, m01 = cw[1]/sy;
    const float m10 = cw[2]/sx, m11 = cw[3]/sy;
    meta[64 + l*8 + 0] = m00;
    meta[64 + l*8 + 1] = m01;
    meta[64 + l*8 + 2] = m10;
    meta[64 + l*8 + 3] = m11;
    meta[64 + l*8 + 4] = -(m00*bx + m01*by);
    meta[64 + l*8 + 5] = -(m10*bx + m11*by);
  }
  if (l == 0 && t == 0) {
    float cst = 0.0f;
    for (int i = 0; i < kDepth; ++i) {
      cst -= logf(fabsf(an_scale[i*2+0]));
      cst -= logf(fabsf(an_scale[i*2+1]));
      const float* cw = conv_w + i * 4;
      float det = cw[0]*cw[3] - cw[1]*cw[2];
      cst += logf(fabsf(det));   // slogdet(conv)[1]
    }
    meta[0] = cst;
  }
}

// ---------------- table: p hoisted to once-per-node, then 4 lanes/node ----------------
__global__ __launch_bounds__(256) void table_kernel(
    const float* __restrict__ an2_scale,
    const float* __restrict__ fc3_w,
    const float* __restrict__ meta, const float* __restrict__ kv,
    const float* __restrict__ CG, const float* __restrict__ CB,
    int tabN, float4* __restrict__ tab)
{
  __shared__ float sKz[128], sKw[128], sKv[128];
  __shared__ int   sP[64];

  const int bpl   = tabN >> 6;               // 64 nodes per block
  const int l     = blockIdx.x / bpl;
  const int node0 = (blockIdx.x % bpl) * 64;
  const int t     = threadIdx.x;
  const float dv  = (kVMax - kVMin) / (float)(tabN - 1);

  if (t < 128) {
    const float si = 1.0f / an2_scale[l*kWidth + t];
    sKz[t] = fc3_w[l*2*kWidth + t] * si;
    sKw[t] = fc3_w[l*2*kWidth + kWidth + t] * si;
    sKv[t] = kv[l*128 + t];
  }
  __syncthreads();

  // phase 1: prefix index once per node (threads 0..63)
  if (t < 64) {
    const float v = kVMin + dv * (float)(node0 + t);
    int p = 0;
    const float4* kv4 = (const float4*)sKv;
#pragma unroll
    for (int m = 0; m < 32; ++m) {
      float4 K = kv4[m];                     // broadcast (lane-uniform addr)
      p += (K.x < v) + (K.y < v) + (K.z < v) + (K.w < v);
    }
    sP[t] = p;
  }
  __syncthreads();

  // phase 2: node = t>>2, kq = t&3 owns 32 k (8 float4 chunks)
  const int node = t >> 2, kq = t & 3;
  const int p = sP[node];
  const float v = kVMin + dv * (float)(node0 + node);

  const float4* cg4 = (const float4*)(CG + ((size_t)l*129 + p) * 128 + kq*32);
  const float4* cb4 = (const float4*)(CB + ((size_t)l*129 + p) * 128 + kq*32);
  const float4* kz4 = (const float4*)sKz + kq*8;
  const float4* kw4 = (const float4*)sKw + kq*8;

  float o0 = 0.f, o1 = 0.f, p0 = 0.f, p1 = 0.f;
#pragma unroll
  for (int c = 0; c < 8; ++c) {
    float4 G = cg4[c], B = cb4[c], Z = kz4[c], W = kw4[c];
    float raw, h, dd;
    raw = fmaf(v, G.x, B.x); h = fmaxf(raw, 0.f); dd = (raw > 0.f) ? G.x : 0.f;
    o0 = fmaf(h, Z.x, o0); o1 = fmaf(h, W.x, o1); p0 = fmaf(dd, Z.x, p0); p1 = fmaf(dd, W.x, p1);
    raw = fmaf(v, G.y, B.y); h = fmaxf(raw, 0.f); dd = (raw > 0.f) ? G.y : 0.f;
    o0 = fmaf(h, Z.y, o0); o1 = fmaf(h, W.y, o1); p0 = fmaf(dd, Z.y, p0); p1 = fmaf(dd, W.y, p1);
    raw = fmaf(v, G.z, B.z); h = fmaxf(raw, 0.f); dd = (raw > 0.f) ? G.z : 0.f;
    o0 = fmaf(h, Z.z, o0); o1 = fmaf(h, W.z, o1); p0 = fmaf(dd, Z.z, p0); p1 = fmaf(dd, W.z, p1);
    raw = fmaf(v, G.w, B.w); h = fmaxf(raw, 0.f); dd = (raw > 0.f) ? G.w : 0.f;
    o0 = fmaf(h, Z.w, o0); o1 = fmaf(h, W.w, o1); p0 = fmaf(dd, Z.w, p0); p1 = fmaf(dd, W.w, p1);
  }

  // reduce over the 4 kq lanes (adjacent in-wave)
  o0 += __shfl_xor(o0, 1); o0 += __shfl_xor(o0, 2);
  o1 += __shfl_xor(o1, 1); o1 += __shfl_xor(o1, 2);
  p0 += __shfl_xor(p0, 1); p0 += __shfl_xor(p0, 2);
  p1 += __shfl_xor(p1, 1); p1 += __shfl_xor(p1, 2);

  if (kq == 0) {
    const float E0  = meta[16 + l*4 + 0];
    const float E1  = meta[16 + l*4 + 1];
    const float b30 = meta[16 + l*4 + 2];
    const float b31 = meta[16 + l*4 + 3];
    tab[(size_t)l * tabN + node0 + node] =
        make_float4((o0 + b30) * E0, p0 * E0, (o1 + b31) * E1, p1 * E1);
  }
}

// ---------------- main: dbuf split-entry LDS table, 4 chains/thread ----------------
__global__ __launch_bounds__(1024) void flow_apply_kernel(
    const float* __restrict__ x,
    const float4* __restrict__ tab, const float* __restrict__ meta,
    int tabN,
    float* __restrict__ out_z, float* __restrict__ out_ld, int n)
{
  __shared__ float2 sTU[2][1024];            // (t, u)   2 x 8 KB
  __shared__ float2 sDT[2][1024];            // (dt, du) 2 x 8 KB

  const int t = threadIdx.x;
  const int base = blockIdx.x * 4096;

  int   sid[4];
  bool  ok[4];
  float2 z[4];
  float ldv[4];
  const float ldc = meta[0];
#pragma unroll
  for (int c = 0; c < 4; ++c) {
    sid[c] = base + c * 1024 + t;
    ok[c] = sid[c] < n;
    z[c] = ok[c] ? reinterpret_cast<const float2*>(x)[sid[c]] : make_float2(0.f, 0.f);
    ldv[c] = ldc;
  }

  const float dv = (kVMax - kVMin) / (float)(tabN - 1);
  const float inv_dv = (float)(tabN - 1) / (kVMax - kVMin);
  const float offv = -kVMin * inv_dv;
  const float qmax = (float)(tabN - 1);
  constexpr float kLog2e = 1.44269504088896340736f;
  constexpr float kLn2   = 0.69314718055994530942f;

  // prologue: stage layer 0 into buffer 0
  if (t < tabN) {
    float4 e = tab[t];
    sTU[0][t] = make_float2(e.x, e.z);
    sDT[0][t] = make_float2(e.y, e.w);
  }
  __syncthreads();

  int cur = 0;
#pragma unroll 1
  for (int i = 0; i < kDepth; ++i) {
    // issue next layer's staging load early (latency hides under compute)
    float4 en = make_float4(0.f, 0.f, 0.f, 0.f);
    if (i + 1 < kDepth && t < tabN)
      en = tab[(size_t)(i + 1) * tabN + t];

    const float m00 = meta[64 + i*8 + 0], m01 = meta[64 + i*8 + 1];
    const float m10 = meta[64 + i*8 + 2], m11 = meta[64 + i*8 + 3];
    const float q0  = meta[64 + i*8 + 4], q1  = meta[64 + i*8 + 5];
    const float2* tu = sTU[cur];
    const float2* dt = sDT[cur];

#pragma unroll
    for (int c = 0; c < 4; ++c) {
      const float na = fmaf(m00, z[c].x, fmaf(m01, z[c].y, q0));
      const float nb = fmaf(m10, z[c].x, fmaf(m11, z[c].y, q1));
      float xq = fmaf(nb, inv_dv, offv);
      xq = fminf(fmaxf(xq, 0.0f), qmax);
      const int qn = (int)(xq + 0.5f);       // nearest node, <= tabN-1
      const float2 e  = tu[qn];
      const float2 de = dt[qn];
      const float vn = fmaf((float)qn, dv, kVMin);
      const float f = nb - vn;
      const float tt = fmaf(f, de.x, e.x);   // tangent line (exact unless
      const float uu = fmaf(f, de.y, e.y);   //  kink in the half-cell)
      // sigmoid / log-sigmoid of arg = uu + 2 via native exp2/log2/rcp
      const float arg = uu + 2.0f;
      const float ev = __builtin_amdgcn_exp2f(arg * -kLog2e);
      const float den = 1.0f + ev;
      const float s = __builtin_amdgcn_rcpf(den);
      ldv[c] = fmaf(-kLn2, __builtin_amdgcn_logf(den), ldv[c]);
      z[c].x = fmaf(s, na, tt);
      z[c].y = nb;
    }

    __syncthreads();                         // all reads of sTab[cur^1] done
    if (i + 1 < kDepth && t < tabN) {
      sTU[cur ^ 1][t] = make_float2(en.x, en.z);
      sDT[cur ^ 1][t] = make_float2(en.y, en.w);
    }
    __syncthreads();                         // next buffer ready
    cur ^= 1;
  }

#pragma unroll
  for (int c = 0; c < 4; ++c) {
    if (ok[c]) {
      reinterpret_cast<float2*>(out_z)[sid[c]] = z[c];
      out_ld[sid[c]] = ldv[c];
    }
  }
}

extern "C" void kernel_launch(void* const* d_in, const int* in_sizes, int n_in,
                              void* d_out, int out_size, void* d_ws, size_t ws_size,
                              hipStream_t stream) {
  const float* x         = (const float*)d_in[0];
  const float* an_scale  = (const float*)d_in[1];
  const float* an_bias   = (const float*)d_in[2];
  const float* conv_w    = (const float*)d_in[3];
  const float* fc1_w     = (const float*)d_in[4];
  const float* fc1_b     = (const float*)d_in[5];
  const float* an1_scale = (const float*)d_in[6];
  const float* an1_bias  = (const float*)d_in[7];
  const float* fc2_w     = (const float*)d_in[8];
  const float* fc2_b     = (const float*)d_in[9];
  const float* an2_scale = (const float*)d_in[10];
  const float* an2_bias  = (const float*)d_in[11];
  const float* fc3_w     = (const float*)d_in[12];
  const float* fc3_b     = (const float*)d_in[13];
  const float* lsf       = (const float*)d_in[14];

  const int n = in_sizes[0] / 2;

  // ws: [meta 256f][kv 1280f][CG 10*129*128 f][CB same][tab]
  const size_t metaF = 256, kvF = (size_t)kDepth * 128;
  const size_t cF = (size_t)kDepth * 129 * 128;
  const size_t headF = metaF + kvF + 2 * cF;
  int tabN = 1024;
  while (tabN > 256 &&
         headF * 4 + (size_t)kDepth * tabN * sizeof(float4) > ws_size) {
    tabN >>= 1;
  }
  float* meta = (float*)d_ws;
  float* kv   = meta + metaF;
  float* CG   = kv + kvF;
  float* CB   = CG + cF;
  float4* tab = (float4*)(CB + cF);

  prep_kernel<<<kDepth, 256, 0, stream>>>(
      an_scale, an_bias, conv_w, fc1_w, fc1_b, an1_scale, an1_bias,
      fc2_w, fc2_b, an2_scale, an2_bias, fc3_b, lsf,
      meta, kv, CG, CB);

  table_kernel<<<kDepth * (tabN / 64), 256, 0, stream>>>(
      an2_scale, fc3_w, meta, kv, CG, CB, tabN, tab);

  const int blocks = (n + 4095) / 4096;
  flow_apply_kernel<<<blocks, 1024, 0, stream>>>(
      x, tab, meta, tabN, (float*)d_out, (float*)d_out + (size_t)2 * n, n);
}

// Round 21
// 40.379 us; speedup vs baseline: 1.1225x; 1.1225x over previous
//
#include <hip/hip_runtime.h>
#include <math.h>

// FlowLevel: DIM=2, half=1 -> per-layer coupling depends on scalar v = z_b.
// t(v) and u(v) (pre-sigmoid) are piecewise-LINEAR in v (ReLU MLP).
// Tabulate (t, dt/dv, u, du/dv) per node; apply uses the NEAREST node's
// tangent line (exact unless a kink falls in the half-cell).
//
// v18: ALL 10 layers resident in LDS at once -> zero barriers in the layer
// loop (r20 killed the conflict/bandwidth theories; residual apply cost is
// the per-layer dbuf barrier convoy + staging issue). tabN=512, (t,u) f32 +
// (dt,du) bf16-packed = 60 KB static LDS; slope quantization contributes
// ~1.5e-3 (slope multiplies |f| <= dv/2). 2 blocks/CU = full occupancy.

constexpr int kDepth = 10;
constexpr int kWidth = 128;
constexpr float kVMin = -24.0f;
constexpr float kVMax =  24.0f;

// ---------------- prep: per-layer kink sort + prefix sweep ----------------
__global__ void prep_kernel(
    const float* __restrict__ an_scale, const float* __restrict__ an_bias,
    const float* __restrict__ conv_w,
    const float* __restrict__ fc1_w, const float* __restrict__ fc1_b,
    const float* __restrict__ an1_scale, const float* __restrict__ an1_bias,
    const float* __restrict__ fc2_w, const float* __restrict__ fc2_b,
    const float* __restrict__ an2_scale, const float* __restrict__ an2_bias,
    const float* __restrict__ fc3_b, const float* __restrict__ lsf,
    float* __restrict__ meta, float* __restrict__ kv,
    float* __restrict__ CG, float* __restrict__ CB)
{
  __shared__ float sWT[128 * 129];           // transposed weights, padded
  __shared__ float sVs[128], sG[128], sB[128];
  __shared__ float sGs[128], sBs[128];       // sig*g, sig*b (sweep deltas)
  __shared__ int   sOrd[128];

  const int l = blockIdx.x;                  // layer
  const int t = threadIdx.x;                 // 0..255

  // transpose fc2_w into sWT[j][k] -- all 256 threads, coalesced
  const float* wl = fc2_w + (size_t)l * kWidth * kWidth;
#pragma unroll 8
  for (int fi = t; fi < 128 * 128; fi += 256) {
    const int k = fi >> 7, j = fi & 127;
    sWT[j * 129 + k] = wl[fi];
  }

  // per-j gate params and kink position
  if (t < 128) {
    const float s1 = an1_scale[l*kWidth + t];
    const float g = fc1_w[l*kWidth + t] / s1;
    const float b = (fc1_b[l*kWidth + t] - an1_bias[l*kWidth + t]) / s1;
    float vs, sg;
    if (g > 0.0f)      { vs = -b / g; sg =  1.0f; }
    else if (g < 0.0f) { vs = -b / g; sg = -1.0f; }
    else               { vs = (b > 0.0f) ? -1e30f : 1e30f; sg = (b > 0.0f) ? 1.0f : 0.0f; }
    sG[t] = g; sB[t] = b; sVs[t] = vs;
    sGs[t] = sg * g; sBs[t] = sg * b;
  }
  __syncthreads();

  // stable rank sort by kink position -- unrolled float4 reads (pipelined)
  if (t < 128) {
    const float my = sVs[t];
    int r = 0;
    const float4* vs4 = (const float4*)sVs;
#pragma unroll
    for (int i4 = 0; i4 < 32; ++i4) {
      float4 o = vs4[i4];
      const int ib = i4 * 4;
      r += (o.x < my) || (o.x == my && ib + 0 < t);
      r += (o.y < my) || (o.y == my && ib + 1 < t);
      r += (o.z < my) || (o.z == my && ib + 2 < t);
      r += (o.w < my) || (o.w == my && ib + 3 < t);
    }
    sOrd[r] = t;
  }
  __syncthreads();

  if (t < 128) {
    kv[l*128 + t] = sVs[sOrd[t]];

    // base C[0] (thread t owns k=t): all neg-g active, plus folded bz.
    float cg = 0.0f;
    float cb = fc2_b[l*kWidth + t] - an2_bias[l*kWidth + t];
    const float4* g4 = (const float4*)sG;
    const float4* b4 = (const float4*)sB;
#pragma unroll
    for (int j4 = 0; j4 < 32; ++j4) {
      float4 G = g4[j4], B = b4[j4];
      const int j = j4 * 4;
      float w0 = sWT[(j + 0) * 129 + t];
      float w1 = sWT[(j + 1) * 129 + t];
      float w2 = sWT[(j + 2) * 129 + t];
      float w3 = sWT[(j + 3) * 129 + t];
      if (G.x < 0.0f) { cg = fmaf(G.x, w0, cg); cb = fmaf(B.x, w0, cb); }
      if (G.y < 0.0f) { cg = fmaf(G.y, w1, cg); cb = fmaf(B.y, w1, cb); }
      if (G.z < 0.0f) { cg = fmaf(G.z, w2, cg); cb = fmaf(B.z, w2, cb); }
      if (G.w < 0.0f) { cg = fmaf(G.w, w3, cg); cb = fmaf(B.w, w3, cb); }
    }

    // sweep, software-pipelined in chunks of 4 (prefetch next chunk)
    const size_t base = (size_t)l * 129 * 128;
    int4 J = ((const int4*)sOrd)[0];
    float w0 = sWT[J.x * 129 + t];
    float w1 = sWT[J.y * 129 + t];
    float w2 = sWT[J.z * 129 + t];
    float w3 = sWT[J.w * 129 + t];
#pragma unroll 1
    for (int c = 0; c < 32; ++c) {
      const int4 Jc = J;
      const float v0 = w0, v1 = w1, v2 = w2, v3 = w3;
      if (c + 1 < 32) {
        J = ((const int4*)sOrd)[c + 1];
        w0 = sWT[J.x * 129 + t];
        w1 = sWT[J.y * 129 + t];
        w2 = sWT[J.z * 129 + t];
        w3 = sWT[J.w * 129 + t];
      }
      const int p = c * 4;
      CG[base + (size_t)(p + 0) * 128 + t] = cg;
      CB[base + (size_t)(p + 0) * 128 + t] = cb;
      cg = fmaf(sGs[Jc.x], v0, cg); cb = fmaf(sBs[Jc.x], v0, cb);
      CG[base + (size_t)(p + 1) * 128 + t] = cg;
      CB[base + (size_t)(p + 1) * 128 + t] = cb;
      cg = fmaf(sGs[Jc.y], v1, cg); cb = fmaf(sBs[Jc.y], v1, cb);
      CG[base + (size_t)(p + 2) * 128 + t] = cg;
      CB[base + (size_t)(p + 2) * 128 + t] = cb;
      cg = fmaf(sGs[Jc.z], v2, cg); cb = fmaf(sBs[Jc.z], v2, cb);
      CG[base + (size_t)(p + 3) * 128 + t] = cg;
      CB[base + (size_t)(p + 3) * 128 + t] = cb;
      cg = fmaf(sGs[Jc.w], v3, cg); cb = fmaf(sBs[Jc.w], v3, cb);
    }
    CG[base + (size_t)128 * 128 + t] = cg;
    CB[base + (size_t)128 * 128 + t] = cb;
  }

  // per-layer epilogue + affine constants
  if (t == 0) {
    meta[16 + l*4 + 0] = expf(lsf[l*2 + 0]);
    meta[16 + l*4 + 1] = expf(lsf[l*2 + 1]);
    meta[16 + l*4 + 2] = fc3_b[l*2 + 0];
    meta[16 + l*4 + 3] = fc3_b[l*2 + 1];

    const float sx = an_scale[l*2+0], sy = an_scale[l*2+1];
    const float bx = an_bias[l*2+0],  by = an_bias[l*2+1];
    const float* cw = conv_w + l*4;
    const float m00 = cw[0]/sx, m01 = cw[1]/sy;
    const float m10 = cw[2]/sx, m11 = cw[3]/sy;
    meta[64 + l*8 + 0] = m00;
    meta[64 + l*8 + 1] = m01;
    meta[64 + l*8 + 2] = m10;
    meta[64 + l*8 + 3] = m11;
    meta[64 + l*8 + 4] = -(m00*bx + m01*by);
    meta[64 + l*8 + 5] = -(m10*bx + m11*by);
  }
  if (l == 0 && t == 0) {
    float cst = 0.0f;
    for (int i = 0; i < kDepth; ++i) {
      cst -= logf(fabsf(an_scale[i*2+0]));
      cst -= logf(fabsf(an_scale[i*2+1]));
      const float* cw = conv_w + i * 4;
      float det = cw[0]*cw[3] - cw[1]*cw[2];
      cst += logf(fabsf(det));   // slogdet(conv)[1]
    }
    meta[0] = cst;
  }
}

// ---------------- table: p hoisted to once-per-node, then 4 lanes/node ----------------
__global__ __launch_bounds__(256) void table_kernel(
    const float* __restrict__ an2_scale,
    const float* __restrict__ fc3_w,
    const float* __restrict__ meta, const float* __restrict__ kv,
    const float* __restrict__ CG, const float* __restrict__ CB,
    int tabN, float4* __restrict__ tab)
{
  __shared__ float sKz[128], sKw[128], sKv[128];
  __shared__ int   sP[64];

  const int bpl   = tabN >> 6;               // 64 nodes per block
  const int l     = blockIdx.x / bpl;
  const int node0 = (blockIdx.x % bpl) * 64;
  const int t     = threadIdx.x;
  const float dv  = (kVMax - kVMin) / (float)(tabN - 1);

  if (t < 128) {
    const float si = 1.0f / an2_scale[l*kWidth + t];
    sKz[t] = fc3_w[l*2*kWidth + t] * si;
    sKw[t] = fc3_w[l*2*kWidth + kWidth + t] * si;
    sKv[t] = kv[l*128 + t];
  }
  __syncthreads();

  // phase 1: prefix index once per node (threads 0..63)
  if (t < 64) {
    const float v = kVMin + dv * (float)(node0 + t);
    int p = 0;
    const float4* kv4 = (const float4*)sKv;
#pragma unroll
    for (int m = 0; m < 32; ++m) {
      float4 K = kv4[m];                     // broadcast (lane-uniform addr)
      p += (K.x < v) + (K.y < v) + (K.z < v) + (K.w < v);
    }
    sP[t] = p;
  }
  __syncthreads();

  // phase 2: node = t>>2, kq = t&3 owns 32 k (8 float4 chunks)
  const int node = t >> 2, kq = t & 3;
  const int p = sP[node];
  const float v = kVMin + dv * (float)(node0 + node);

  const float4* cg4 = (const float4*)(CG + ((size_t)l*129 + p) * 128 + kq*32);
  const float4* cb4 = (const float4*)(CB + ((size_t)l*129 + p) * 128 + kq*32);
  const float4* kz4 = (const float4*)sKz + kq*8;
  const float4* kw4 = (const float4*)sKw + kq*8;

  float o0 = 0.f, o1 = 0.f, p0 = 0.f, p1 = 0.f;
#pragma unroll
  for (int c = 0; c < 8; ++c) {
    float4 G = cg4[c], B = cb4[c], Z = kz4[c], W = kw4[c];
    float raw, h, dd;
    raw = fmaf(v, G.x, B.x); h = fmaxf(raw, 0.f); dd = (raw > 0.f) ? G.x : 0.f;
    o0 = fmaf(h, Z.x, o0); o1 = fmaf(h, W.x, o1); p0 = fmaf(dd, Z.x, p0); p1 = fmaf(dd, W.x, p1);
    raw = fmaf(v, G.y, B.y); h = fmaxf(raw, 0.f); dd = (raw > 0.f) ? G.y : 0.f;
    o0 = fmaf(h, Z.y, o0); o1 = fmaf(h, W.y, o1); p0 = fmaf(dd, Z.y, p0); p1 = fmaf(dd, W.y, p1);
    raw = fmaf(v, G.z, B.z); h = fmaxf(raw, 0.f); dd = (raw > 0.f) ? G.z : 0.f;
    o0 = fmaf(h, Z.z, o0); o1 = fmaf(h, W.z, o1); p0 = fmaf(dd, Z.z, p0); p1 = fmaf(dd, W.z, p1);
    raw = fmaf(v, G.w, B.w); h = fmaxf(raw, 0.f); dd = (raw > 0.f) ? G.w : 0.f;
    o0 = fmaf(h, Z.w, o0); o1 = fmaf(h, W.w, o1); p0 = fmaf(dd, Z.w, p0); p1 = fmaf(dd, W.w, p1);
  }

  // reduce over the 4 kq lanes (adjacent in-wave)
  o0 += __shfl_xor(o0, 1); o0 += __shfl_xor(o0, 2);
  o1 += __shfl_xor(o1, 1); o1 += __shfl_xor(o1, 2);
  p0 += __shfl_xor(p0, 1); p0 += __shfl_xor(p0, 2);
  p1 += __shfl_xor(p1, 1); p1 += __shfl_xor(p1, 2);

  if (kq == 0) {
    const float E0  = meta[16 + l*4 + 0];
    const float E1  = meta[16 + l*4 + 1];
    const float b30 = meta[16 + l*4 + 2];
    const float b31 = meta[16 + l*4 + 3];
    tab[(size_t)l * tabN + node0 + node] =
        make_float4((o0 + b30) * E0, p0 * E0, (o1 + b31) * E1, p1 * E1);
  }
}

// bf16 round-to-nearest-even pack of two floats
__device__ __forceinline__ unsigned int pack_bf16(float a, float b) {
  unsigned int ua = __float_as_uint(a);
  unsigned int ub = __float_as_uint(b);
  ua = (ua + 0x7FFFu + ((ua >> 16) & 1u)) >> 16;
  ub = (ub + 0x7FFFu + ((ub >> 16) & 1u)) >> 16;
  return ua | (ub << 16);
}

// ---------------- main: whole table in LDS, barrier-free layer loop ----------------
__global__ __launch_bounds__(1024) void flow_apply_kernel(
    const float* __restrict__ x,
    const float4* __restrict__ tab, const float* __restrict__ meta,
    int tabN,
    float* __restrict__ out_z, float* __restrict__ out_ld, int n)
{
  __shared__ float2       sTU[kDepth * 512];   // (t, u)      40 KB
  __shared__ unsigned int sPK[kDepth * 512];   // bf16 dt,du  20 KB

  const int t = threadIdx.x;
  const int base = blockIdx.x * 4096;

  // stage all layers once (coalesced), convert to split/compressed form
  for (int j = t; j < kDepth * tabN; j += 1024) {
    float4 e = tab[j];
    sTU[j] = make_float2(e.x, e.z);
    sPK[j] = pack_bf16(e.y, e.w);
  }

  int   sid[4];
  bool  ok[4];
  float2 z[4];
  float ldv[4];
  const float ldc = meta[0];
#pragma unroll
  for (int c = 0; c < 4; ++c) {
    sid[c] = base + c * 1024 + t;
    ok[c] = sid[c] < n;
    z[c] = ok[c] ? reinterpret_cast<const float2*>(x)[sid[c]] : make_float2(0.f, 0.f);
    ldv[c] = ldc;
  }

  const float dv = (kVMax - kVMin) / (float)(tabN - 1);
  const float inv_dv = (float)(tabN - 1) / (kVMax - kVMin);
  const float offv = -kVMin * inv_dv;
  const float qmax = (float)(tabN - 1);
  constexpr float kLog2e = 1.44269504088896340736f;
  constexpr float kLn2   = 0.69314718055994530942f;

  __syncthreads();                           // table ready; no more barriers

#pragma unroll 1
  for (int i = 0; i < kDepth; ++i) {
    const float m00 = meta[64 + i*8 + 0], m01 = meta[64 + i*8 + 1];
    const float m10 = meta[64 + i*8 + 2], m11 = meta[64 + i*8 + 3];
    const float q0  = meta[64 + i*8 + 4], q1  = meta[64 + i*8 + 5];
    const float2* tu = sTU + i * tabN;
    const unsigned int* pk = sPK + i * tabN;

#pragma unroll
    for (int c = 0; c < 4; ++c) {
      const float na = fmaf(m00, z[c].x, fmaf(m01, z[c].y, q0));
      const float nb = fmaf(m10, z[c].x, fmaf(m11, z[c].y, q1));
      float xq = fmaf(nb, inv_dv, offv);
      xq = fminf(fmaxf(xq, 0.0f), qmax);
      const int qn = (int)(xq + 0.5f);       // nearest node, <= tabN-1
      const float2 e = tu[qn];
      const unsigned int d = pk[qn];
      const float dt = __uint_as_float(d << 16);
      const float du = __uint_as_float(d & 0xFFFF0000u);
      const float vn = fmaf((float)qn, dv, kVMin);
      const float f = nb - vn;
      const float tt = fmaf(f, dt, e.x);     // tangent line (exact unless
      const float uu = fmaf(f, du, e.y);     //  kink in the half-cell)
      // sigmoid / log-sigmoid of arg = uu + 2 via native exp2/log2/rcp
      const float arg = uu + 2.0f;
      const float ev = __builtin_amdgcn_exp2f(arg * -kLog2e);
      const float den = 1.0f + ev;
      const float s = __builtin_amdgcn_rcpf(den);
      ldv[c] = fmaf(-kLn2, __builtin_amdgcn_logf(den), ldv[c]);
      z[c].x = fmaf(s, na, tt);
      z[c].y = nb;
    }
  }

#pragma unroll
  for (int c = 0; c < 4; ++c) {
    if (ok[c]) {
      reinterpret_cast<float2*>(out_z)[sid[c]] = z[c];
      out_ld[sid[c]] = ldv[c];
    }
  }
}

extern "C" void kernel_launch(void* const* d_in, const int* in_sizes, int n_in,
                              void* d_out, int out_size, void* d_ws, size_t ws_size,
                              hipStream_t stream) {
  const float* x         = (const float*)d_in[0];
  const float* an_scale  = (const float*)d_in[1];
  const float* an_bias   = (const float*)d_in[2];
  const float* conv_w    = (const float*)d_in[3];
  const float* fc1_w     = (const float*)d_in[4];
  const float* fc1_b     = (const float*)d_in[5];
  const float* an1_scale = (const float*)d_in[6];
  const float* an1_bias  = (const float*)d_in[7];
  const float* fc2_w     = (const float*)d_in[8];
  const float* fc2_b     = (const float*)d_in[9];
  const float* an2_scale = (const float*)d_in[10];
  const float* an2_bias  = (const float*)d_in[11];
  const float* fc3_w     = (const float*)d_in[12];
  const float* fc3_b     = (const float*)d_in[13];
  const float* lsf       = (const float*)d_in[14];

  const int n = in_sizes[0] / 2;

  // ws: [meta 256f][kv 1280f][CG 10*129*128 f][CB same][tab]
  const size_t metaF = 256, kvF = (size_t)kDepth * 128;
  const size_t cF = (size_t)kDepth * 129 * 128;
  const size_t headF = metaF + kvF + 2 * cF;
  int tabN = 512;
  while (tabN > 128 &&
         headF * 4 + (size_t)kDepth * tabN * sizeof(float4) > ws_size) {
    tabN >>= 1;
  }
  float* meta = (float*)d_ws;
  float* kv   = meta + metaF;
  float* CG   = kv + kvF;
  float* CB   = CG + cF;
  float4* tab = (float4*)(CB + cF);

  prep_kernel<<<kDepth, 256, 0, stream>>>(
      an_scale, an_bias, conv_w, fc1_w, fc1_b, an1_scale, an1_bias,
      fc2_w, fc2_b, an2_scale, an2_bias, fc3_b, lsf,
      meta, kv, CG, CB);

  table_kernel<<<kDepth * (tabN / 64), 256, 0, stream>>>(
      an2_scale, fc3_w, meta, kv, CG, CB, tabN, tab);

  const int blocks = (n + 4095) / 4096;
  flow_apply_kernel<<<blocks, 1024, 0, stream>>>(
      x, tab, meta, tabN, (float*)d_out, (float*)d_out + (size_t)2 * n, n);
}